// Round 6
// baseline (385.737 us; speedup 1.0000x reference)
//
#include <hip/hip_runtime.h>
#include <hip/hip_bf16.h>
#include <math.h>

#define N_BATCH 128
#define C_CH    512
#define HF      38
#define WF      38
#define K1      25088   // 512*49
#define NH      4096
#define NCLS    21
#define NBOX    80
#define STEPS1  784     // K1/32
#define STEPS2  128     // NH/32

typedef __attribute__((ext_vector_type(8))) short s16x8;
typedef __attribute__((ext_vector_type(4))) float f32x4;

// fp32 -> 3x bf16 split (RNE): x ~= b0+b1+b2, residual ~ |x|*2^-25
__device__ __forceinline__ unsigned short bf_rne(float x) {
  unsigned u = __float_as_uint(x);
  return (unsigned short)((u + 0x7FFFu + ((u >> 16) & 1u)) >> 16);
}
__device__ __forceinline__ float bf2f(unsigned short b) {
  return __uint_as_float(((unsigned)b) << 16);
}
__device__ __forceinline__ void split3(float x, unsigned short& q0,
                                       unsigned short& q1, unsigned short& q2) {
  q0 = bf_rne(x); float r1 = x - bf2f(q0);
  q1 = bf_rne(r1); float r2 = r1 - bf2f(q1);
  q2 = bf_rne(r2);
}

__device__ __forceinline__ void gload16(const void* g, void* l) {
  __builtin_amdgcn_global_load_lds(
      (const __attribute__((address_space(1))) unsigned int*)g,
      (__attribute__((address_space(3))) unsigned int*)l, 16, 0, 0);
}

// ---------------------------------------------------------------------------
// Kernel 1: ROI crop + adaptive 7x7 maxpool -> flat fp32 [128][K1]
// ---------------------------------------------------------------------------
__global__ __launch_bounds__(256) void pool_kernel(
    const float* __restrict__ x, const int* __restrict__ rp,
    float* __restrict__ flat) {
  const int n = blockIdx.y, cb = blockIdx.x, tid = threadIdx.x;
  const int r = rp[n*4+0], c = rp[n*4+1], w = rp[n*4+2], h = rp[n*4+3];
  __shared__ float tile[8][24][25];
  const int ch = tid >> 5, l32 = tid & 31;
  const float* xc = x + (((size_t)(n*C_CH + cb*8 + ch))*HF + c)*WF + r;
  for (int y = 0; y < h; ++y)
    for (int xx = l32; xx < w; xx += 32)
      tile[ch][y][xx] = xc[y*WF + xx];
  __syncthreads();
  for (int o = tid; o < 8*49; o += 256) {
    int ch2 = o / 49, ij = o - ch2*49, i = ij / 7, j = ij - i*7;
    int rs = (i*h)/7, re = ((i+1)*h + 6)/7;
    int cs = (j*w)/7, ce = ((j+1)*w + 6)/7;
    float m = -INFINITY;
    for (int y = rs; y < re; ++y)
      for (int xx = cs; xx < ce; ++xx)
        m = fmaxf(m, tile[ch2][y][xx]);
    flat[(size_t)n*K1 + (cb*8+ch2)*49 + ij] = m;
  }
}

// ---------------------------------------------------------------------------
// Kernel 2: fp32 [128][ld] -> 3 bf16 planes in MFMA fragment order.
// ---------------------------------------------------------------------------
__global__ __launch_bounds__(256) void convert_kernel(
    const float* __restrict__ flat, unsigned short* __restrict__ Asw, int ld) {
  const int S = blockIdx.x, t = threadIdx.x;
  const int mt = t >> 5, g2 = (t >> 4) & 1, mlo = t & 15;
  #pragma unroll
  for (int gg = 0; gg < 2; ++gg) {
    const int g = g2 + gg*2;
    const float* src = flat + (size_t)(mt*16 + mlo)*ld + S*32 + g*8;
    float v[8];
    *(float4*)&v[0] = *(const float4*)src;
    *(float4*)&v[4] = *(const float4*)(src + 4);
    unsigned short q[3][8];
    #pragma unroll
    for (int e = 0; e < 8; ++e) split3(v[e], q[0][e], q[1][e], q[2][e]);
    size_t base = (size_t)S*12288 + mt*512 + (size_t)(g*16 + mlo)*8;
    #pragma unroll
    for (int p = 0; p < 3; ++p) {
      ushort4 lo; lo.x=q[p][0]; lo.y=q[p][1]; lo.z=q[p][2]; lo.w=q[p][3];
      ushort4 hi; hi.x=q[p][4]; hi.y=q[p][5]; hi.z=q[p][6]; hi.w=q[p][7];
      *(ushort4*)(Asw + base + p*4096)     = lo;
      *(ushort4*)(Asw + base + p*4096 + 4) = hi;
    }
  }
}

// ---------------------------------------------------------------------------
// Kernel 3: barrier-free split-K MFMA GEMM, register-lean (no manual A
// prefetch; no min-waves clause -> no 128-VGPR spill wall). BM=128, BN=128,
// BK=32, 4 waves; wave-private double-buffered 4KB LDS B-slice staged via
// global_load_lds with pre-swizzled cols; sync = counted vmcnt only.
// ---------------------------------------------------------------------------
__global__ __launch_bounds__(256) void gemm_v5(
    const unsigned short* __restrict__ Asw, const float* __restrict__ B,
    float* __restrict__ part, const int nsteps) {
  __shared__ float Bsm[4][2][32][32];    // [wave][dbuf][k][col'] = 32 KB
  const int tid = threadIdx.x, lane = tid & 63, wv = tid >> 6;
  const int nb = blockIdx.x, ks = blockIdx.y;
  const int l15 = lane & 15, g = lane >> 4;
  const unsigned short* Ab = Asw + (size_t)ks * nsteps * 12288;
  const int srow = lane >> 3, scol = lane & 7;
  const float* Bg = B + ((size_t)ks*nsteps*32 + srow)*NH
                  + (size_t)nb*128 + wv*32;
  float* lds0 = &Bsm[wv][0][0][0];

  f32x4 acc[8][2];
  #pragma unroll
  for (int i = 0; i < 8; ++i)
    #pragma unroll
    for (int j = 0; j < 2; ++j) acc[i][j] = (f32x4){0.f, 0.f, 0.f, 0.f};

  // prologue: stage step 0 into buf 0
  #pragma unroll
  for (int i = 0; i < 4; ++i)
    gload16(Bg + (size_t)(i*8)*NH + ((scol ^ (2*i)) << 2), lds0 + i*256);

  int cur = 0;
  for (int s = 0; s < nsteps; ++s) {
    if (s + 1 < nsteps) {   // stage next step into other buffer, then wait
      const float* Bn = Bg + (size_t)(s+1)*32*NH;
      float* ldsn = lds0 + (cur ^ 1)*1024;
      #pragma unroll
      for (int i = 0; i < 4; ++i)
        gload16(Bn + (size_t)(i*8)*NH + ((scol ^ (2*i)) << 2), ldsn + i*256);
      asm volatile("s_waitcnt vmcnt(4)" ::: "memory");  // drain all but new 4
    } else {
      asm volatile("s_waitcnt vmcnt(0)" ::: "memory");
    }
    // B fragments: lane needs B[k=g*8+e][col=nt*16+l15] ->
    // LDS(row=g*8+e, col' = col ^ (8g)); <=2-way banks.
    const float* bb = lds0 + cur*1024;
    s16x8 bf0[2], bf1[2], bf2[2];
    #pragma unroll
    for (int nt = 0; nt < 2; ++nt) {
      #pragma unroll
      for (int e = 0; e < 8; ++e) {
        float xv = bb[(g*8 + e)*32 + ((nt*16 + l15) ^ (g*8))];
        unsigned short q0, q1, q2; split3(xv, q0, q1, q2);
        bf0[nt][e] = (short)q0; bf1[nt][e] = (short)q1; bf2[nt][e] = (short)q2;
      }
    }
    const unsigned short* As = Ab + (size_t)s*12288 + lane*8;
    #pragma unroll
    for (int mt = 0; mt < 8; ++mt) {
      const s16x8 a0 = *(const s16x8*)(As + mt*512);
      const s16x8 a1 = *(const s16x8*)(As + 4096 + mt*512);
      const s16x8 a2 = *(const s16x8*)(As + 8192 + mt*512);
      #pragma unroll
      for (int nt = 0; nt < 2; ++nt) {
        f32x4 cc = acc[mt][nt];
        cc = __builtin_amdgcn_mfma_f32_16x16x32_bf16(a0, bf0[nt], cc, 0, 0, 0);
        cc = __builtin_amdgcn_mfma_f32_16x16x32_bf16(a0, bf1[nt], cc, 0, 0, 0);
        cc = __builtin_amdgcn_mfma_f32_16x16x32_bf16(a1, bf0[nt], cc, 0, 0, 0);
        cc = __builtin_amdgcn_mfma_f32_16x16x32_bf16(a0, bf2[nt], cc, 0, 0, 0);
        cc = __builtin_amdgcn_mfma_f32_16x16x32_bf16(a1, bf1[nt], cc, 0, 0, 0);
        cc = __builtin_amdgcn_mfma_f32_16x16x32_bf16(a2, bf0[nt], cc, 0, 0, 0);
        acc[mt][nt] = cc;
      }
    }
    cur ^= 1;
  }
  float* Pb = part + (size_t)ks*N_BATCH*NH + (size_t)nb*128 + wv*32;
  #pragma unroll
  for (int mt = 0; mt < 8; ++mt)
    #pragma unroll
    for (int nt = 0; nt < 2; ++nt)
      #pragma unroll
      for (int rr = 0; rr < 4; ++rr)
        Pb[(size_t)(mt*16 + g*4 + rr)*NH + nt*16 + l15] = acc[mt][nt][rr];
}

// ---------------------------------------------------------------------------
// Kernel 4: reduce split-K partials + bias + relu.
// mode 0: also emit swizzled bf16 planes for the next GEMM (fused convert).
// mode 1: write fp32 rows.
// ---------------------------------------------------------------------------
__global__ __launch_bounds__(256) void reduce_k(
    const float* __restrict__ part, const float* __restrict__ bias,
    unsigned short* __restrict__ AswOut, float* __restrict__ f32out,
    int KS, int mode) {
  const int idx = blockIdx.x*256 + threadIdx.x;     // float4 idx, 131072 total
  float4 s = ((const float4*)part)[idx];
  for (int k2 = 1; k2 < KS; ++k2) {
    float4 p = ((const float4*)part)[(size_t)k2*131072 + idx];
    s.x += p.x; s.y += p.y; s.z += p.z; s.w += p.w;
  }
  float4 bv = ((const float4*)bias)[idx & 1023];
  float v[4];
  v[0] = fmaxf(s.x + bv.x, 0.f); v[1] = fmaxf(s.y + bv.y, 0.f);
  v[2] = fmaxf(s.z + bv.z, 0.f); v[3] = fmaxf(s.w + bv.w, 0.f);
  if (mode == 1) {
    float4 o; o.x = v[0]; o.y = v[1]; o.z = v[2]; o.w = v[3];
    ((float4*)f32out)[idx] = o;
  } else {
    int m = idx >> 10, k = (idx & 1023) * 4;
    int S = k >> 5, g = (k >> 3) & 3, e0 = k & 7;
    size_t base = (size_t)S*12288 + (size_t)(m >> 4)*512
                + (size_t)(g*16 + (m & 15))*8 + e0;
    unsigned short q[3][4];
    #pragma unroll
    for (int e = 0; e < 4; ++e) split3(v[e], q[0][e], q[1][e], q[2][e]);
    #pragma unroll
    for (int p = 0; p < 3; ++p) {
      ushort4 st; st.x=q[p][0]; st.y=q[p][1]; st.z=q[p][2]; st.w=q[p][3];
      *(ushort4*)(AswOut + base + p*4096) = st;
    }
  }
}

// ---------------------------------------------------------------------------
// Kernel 5a: transpose Wcls|Wbox into WT[101][4096]
// ---------------------------------------------------------------------------
__global__ __launch_bounds__(256) void head_transpose(
    const float* __restrict__ Wcls, const float* __restrict__ Wbox,
    float* __restrict__ WT) {
  const int c = blockIdx.x;
  const float* src; int stride;
  if (c < NCLS) { src = Wcls + c; stride = NCLS; }
  else          { src = Wbox + (c - NCLS); stride = NBOX; }
  for (int k = threadIdx.x; k < NH; k += 256)
    WT[(size_t)c*NH + k] = src[(size_t)k*stride];
}

// ---------------------------------------------------------------------------
// Kernel 5b: one wave per (n, col): float4 dot over K=4096 + shuffle reduce
// ---------------------------------------------------------------------------
__global__ __launch_bounds__(256) void head_dots(
    const float* __restrict__ h2, const float* __restrict__ WT,
    float* __restrict__ hout) {
  const int n = blockIdx.y;
  const int wv = threadIdx.x >> 6, lane = threadIdx.x & 63;
  const int c = blockIdx.x * 4 + wv;
  if (c >= NCLS + NBOX) return;
  const float4* hp = (const float4*)(h2 + (size_t)n*NH);
  const float4* wp = (const float4*)(WT + (size_t)c*NH);
  float s0=0.f, s1=0.f, s2=0.f, s3=0.f;
  #pragma unroll
  for (int it = 0; it < 16; ++it) {
    float4 a = hp[it*64 + lane];
    float4 b = wp[it*64 + lane];
    s0 = fmaf(a.x, b.x, s0); s1 = fmaf(a.y, b.y, s1);
    s2 = fmaf(a.z, b.z, s2); s3 = fmaf(a.w, b.w, s3);
  }
  float v = (s0 + s1) + (s2 + s3);
  #pragma unroll
  for (int m = 32; m >= 1; m >>= 1) v += __shfl_xor(v, m, 64);
  if (lane == 0) hout[n*128 + c] = v;
}

// ---------------------------------------------------------------------------
// Kernel 5c: softmax(21) + bbox(80) from stored dots.
// ---------------------------------------------------------------------------
__global__ __launch_bounds__(128) void head_final(
    const float* __restrict__ hout, const int* __restrict__ rp,
    float* __restrict__ out) {
  const int n = blockIdx.x, tid = threadIdx.x;
  __shared__ float logits[NCLS];
  __shared__ float red[2];
  if (tid < NCLS) logits[tid] = hout[n*128 + tid];
  __syncthreads();
  if (tid == 0) {
    float m = logits[0];
    for (int i = 1; i < NCLS; ++i) m = fmaxf(m, logits[i]);
    float s = 0.f;
    for (int i = 0; i < NCLS; ++i) s += expf(logits[i] - m);
    red[0] = m; red[1] = s;
  }
  __syncthreads();
  if (tid < NCLS) {
    out[(size_t)n*NCLS + tid] = expf(logits[tid] - red[0]) / red[1];
  } else if (tid < NCLS + NBOX) {
    const int j = tid - NCLS;
    const float t  = hout[n*128 + tid];
    const float rf = (float)rp[n*4+0];
    const float cf = (float)rp[n*4+1];
    const float wf = (float)rp[n*4+2];
    const float hf = (float)rp[n*4+3];
    float p;
    switch (j & 3) {
      case 0:  p = ceilf (__fmul_rn(__fadd_rn(__fmul_rn(wf, t), rf), 16.f)) - 1.f; break;
      case 1:  p = ceilf (__fmul_rn(__fadd_rn(__fmul_rn(hf, t), cf), 16.f)) - 1.f; break;
      case 2:  p = floorf(__fmul_rn(__fmul_rn(wf, expf(t)), 16.f)) + 1.f; break;
      default: p = floorf(__fmul_rn(__fmul_rn(hf, expf(t)), 16.f)) + 1.f; break;
    }
    out[(size_t)N_BATCH*NCLS + (size_t)n*NBOX + j] = p;
  }
}

// ---------------------------------------------------------------------------
extern "C" void kernel_launch(void* const* d_in, const int* in_sizes, int n_in,
                              void* d_out, int out_size, void* d_ws, size_t ws_size,
                              hipStream_t stream) {
  const float* x    = (const float*)d_in[0];
  const int*   rp   = (const int*)  d_in[1];
  const float* W1   = (const float*)d_in[2];
  const float* b1   = (const float*)d_in[3];
  const float* W2   = (const float*)d_in[4];
  const float* b2   = (const float*)d_in[5];
  const float* Wcls = (const float*)d_in[6];
  const float* Wbox = (const float*)d_in[7];
  float* out = (float*)d_out;

  // ws: flat | Asw1 | Asw2 | h2f | WT | hout | part
  char* wp = (char*)d_ws;
  float* flat = (float*)wp;           wp += (size_t)N_BATCH*K1*4;
  unsigned short* Asw1 = (unsigned short*)wp; wp += (size_t)STEPS1*24576;
  unsigned short* Asw2 = (unsigned short*)wp; wp += (size_t)STEPS2*24576;
  float* h2f = (float*)wp;            wp += (size_t)N_BATCH*NH*4;
  float* WT  = (float*)wp;            wp += (size_t)(NCLS+NBOX)*NH*4;
  float* hout = (float*)wp;           wp += (size_t)N_BATCH*128*4;
  float* part = (float*)wp;
  const size_t fixed = (size_t)(wp - (char*)d_ws);
  const size_t slab = (size_t)N_BATCH*NH*4;       // 2 MB per partial
  int KS1 = 28, KS2 = 32;                          // 784/28=28, 128/32=4
  if (fixed + 32*slab > ws_size) { KS1 = 16; KS2 = 16; }
  if (fixed + (size_t)((KS1>KS2)?KS1:KS2)*slab > ws_size) { KS1 = 8; KS2 = 8; }

  pool_kernel<<<dim3(64, 128), 256, 0, stream>>>(x, rp, flat);
  convert_kernel<<<dim3(STEPS1), 256, 0, stream>>>(flat, Asw1, K1);
  head_transpose<<<dim3(NCLS + NBOX), 256, 0, stream>>>(Wcls, Wbox, WT);

  gemm_v5<<<dim3(32, KS1), 256, 0, stream>>>(Asw1, W1, part, STEPS1/KS1);
  reduce_k<<<dim3(512), 256, 0, stream>>>(part, b1, Asw2, nullptr, KS1, 0);

  gemm_v5<<<dim3(32, KS2), 256, 0, stream>>>(Asw2, W2, part, STEPS2/KS2);
  reduce_k<<<dim3(512), 256, 0, stream>>>(part, b2, nullptr, h2f, KS2, 1);

  head_dots<<<dim3(26, 128), 256, 0, stream>>>(h2f, WT, hout);
  head_final<<<dim3(128), 128, 0, stream>>>(hout, rp, out);
}

// Round 8
// 312.676 us; speedup vs baseline: 1.2337x; 1.2337x over previous
//
#include <hip/hip_runtime.h>
#include <hip/hip_bf16.h>
#include <math.h>

#define N_BATCH 128
#define C_CH    512
#define HF      38
#define WF      38
#define K1      25088   // 512*49
#define NH      4096
#define NCLS    21
#define NBOX    80
#define STEPS1  784     // K1/32
#define STEPS2  128     // NH/32

typedef __attribute__((ext_vector_type(8))) short s16x8;
typedef __attribute__((ext_vector_type(4))) float f32x4;

// fp32 -> 3x bf16 split (RNE): x ~= b0+b1+b2, residual ~ |x|*2^-25
__device__ __forceinline__ unsigned short bf_rne(float x) {
  unsigned u = __float_as_uint(x);
  return (unsigned short)((u + 0x7FFFu + ((u >> 16) & 1u)) >> 16);
}
__device__ __forceinline__ float bf2f(unsigned short b) {
  return __uint_as_float(((unsigned)b) << 16);
}
__device__ __forceinline__ void split3(float x, unsigned short& q0,
                                       unsigned short& q1, unsigned short& q2) {
  q0 = bf_rne(x); float r1 = x - bf2f(q0);
  q1 = bf_rne(r1); float r2 = r1 - bf2f(q1);
  q2 = bf_rne(r2);
}

__device__ __forceinline__ void gload16(const void* g, void* l) {
  __builtin_amdgcn_global_load_lds(
      (const __attribute__((address_space(1))) unsigned int*)g,
      (__attribute__((address_space(3))) unsigned int*)l, 16, 0, 0);
}

// ---------------------------------------------------------------------------
// Kernel 1: ROI crop + adaptive 7x7 maxpool -> flat fp32 [128][K1]
// ---------------------------------------------------------------------------
__global__ __launch_bounds__(256) void pool_kernel(
    const float* __restrict__ x, const int* __restrict__ rp,
    float* __restrict__ flat) {
  const int n = blockIdx.y, cb = blockIdx.x, tid = threadIdx.x;
  const int r = rp[n*4+0], c = rp[n*4+1], w = rp[n*4+2], h = rp[n*4+3];
  __shared__ float tile[8][24][25];
  const int ch = tid >> 5, l32 = tid & 31;
  const float* xc = x + (((size_t)(n*C_CH + cb*8 + ch))*HF + c)*WF + r;
  for (int y = 0; y < h; ++y)
    for (int xx = l32; xx < w; xx += 32)
      tile[ch][y][xx] = xc[y*WF + xx];
  __syncthreads();
  for (int o = tid; o < 8*49; o += 256) {
    int ch2 = o / 49, ij = o - ch2*49, i = ij / 7, j = ij - i*7;
    int rs = (i*h)/7, re = ((i+1)*h + 6)/7;
    int cs = (j*w)/7, ce = ((j+1)*w + 6)/7;
    float m = -INFINITY;
    for (int y = rs; y < re; ++y)
      for (int xx = cs; xx < ce; ++xx)
        m = fmaxf(m, tile[ch2][y][xx]);
    flat[(size_t)n*K1 + (cb*8+ch2)*49 + ij] = m;
  }
}

// ---------------------------------------------------------------------------
// Kernel 2: fp32 [128][ld] -> 3 bf16 planes, GROUP-MAJOR fragment order:
// group g = S*8 + mt (S = k>>5, mt = m>>4); addr = g*1536 + plane*512
// + lane*8 + e, lane = ((k>>3)&3)*16 + (m&15), e = k&7.  (shorts)
// ---------------------------------------------------------------------------
__global__ __launch_bounds__(256) void convert_kernel(
    const float* __restrict__ flat, unsigned short* __restrict__ Asw, int ld) {
  const int S = blockIdx.x, t = threadIdx.x;
  const int mt = t >> 5, g2 = (t >> 4) & 1, mlo = t & 15;
  #pragma unroll
  for (int gg = 0; gg < 2; ++gg) {
    const int kg = g2 + gg*2;
    const float* src = flat + (size_t)(mt*16 + mlo)*ld + S*32 + kg*8;
    float v[8];
    *(float4*)&v[0] = *(const float4*)src;
    *(float4*)&v[4] = *(const float4*)(src + 4);
    unsigned short q[3][8];
    #pragma unroll
    for (int e = 0; e < 8; ++e) split3(v[e], q[0][e], q[1][e], q[2][e]);
    size_t base = ((size_t)S*8 + mt)*1536 + (size_t)(kg*16 + mlo)*8;
    #pragma unroll
    for (int p = 0; p < 3; ++p) {
      ushort4 lo; lo.x=q[p][0]; lo.y=q[p][1]; lo.z=q[p][2]; lo.w=q[p][3];
      ushort4 hi; hi.x=q[p][4]; hi.y=q[p][5]; hi.z=q[p][6]; hi.w=q[p][7];
      *(ushort4*)(Asw + base + p*512)     = lo;
      *(ushort4*)(Asw + base + p*512 + 4) = hi;
    }
  }
}

// ---------------------------------------------------------------------------
// Kernel 3: barrier-free split-K MFMA GEMM with deep dual pipelines.
// BM=128, BN=128, BK=32, 4 waves; wave owns cols [wv*32, wv*32+32).
// A: flat (step,mt)-group software pipeline, 4-slot register window,
//    prefetch distance 4 groups (~460cy cover vs ~200cy L2 latency).
// B: wave-private LDS slice, 3-deep rotation (stage s+2 during s) via
//    global_load_lds with pre-swizzled source cols; one counted
//    s_waitcnt vmcnt(14) per step; NO __syncthreads anywhere.
// ---------------------------------------------------------------------------
__global__ __launch_bounds__(256, 2) void gemm_v6(
    const unsigned short* __restrict__ Asw, const float* __restrict__ B,
    float* __restrict__ part, const int nsteps) {
  __shared__ float Bsm[4][3][32][32];   // [wave][buf][k][col'] = 48 KB
  const int tid = threadIdx.x, lane = tid & 63, wv = tid >> 6;
  const int nb = blockIdx.x, ks = blockIdx.y;
  const int l15 = lane & 15, lq = lane >> 4;
  const unsigned short* Ag = Asw + (size_t)ks*nsteps*12288 + lane*8;
  const int srow = lane >> 3, scol = lane & 7;
  const float* Bg = B + ((size_t)ks*nsteps*32 + srow)*NH
                  + (size_t)nb*128 + wv*32;

  f32x4 acc[8][2];
  #pragma unroll
  for (int i = 0; i < 8; ++i)
    #pragma unroll
    for (int j = 0; j < 2; ++j) acc[i][j] = (f32x4){0.f, 0.f, 0.f, 0.f};

  s16x8 w0[4], w1[4], w2[4];          // 4-slot A window (group-major)
#define LOADA(slot, g) do { \
    const unsigned short* ap_ = Ag + (size_t)(g)*1536; \
    w0[slot] = *(const s16x8*)ap_; \
    w1[slot] = *(const s16x8*)(ap_ + 512); \
    w2[slot] = *(const s16x8*)(ap_ + 1024); } while (0)

  float* bA = &Bsm[wv][0][0][0];
  float* bB = &Bsm[wv][1][0][0];
  float* bC = &Bsm[wv][2][0][0];
#define STAGEB(s, dst) do { \
    const float* bs_ = Bg + (size_t)(s)*32*NH; \
    _Pragma("unroll") \
    for (int i_ = 0; i_ < 4; ++i_) \
      gload16(bs_ + (size_t)(i_*8)*NH + ((scol ^ (2*i_)) << 2), (dst) + i_*256); \
    } while (0)

  STAGEB(0, bA); STAGEB(1, bB);
  LOADA(0, 0); LOADA(1, 1); LOADA(2, 2); LOADA(3, 3);

  for (int s = 0; s < nsteps; ++s) {
    if (s + 2 < nsteps) STAGEB(s + 2, bC);
    asm volatile("s_waitcnt vmcnt(14)" ::: "memory");   // B(s) landed
    // B fragments: lane needs B[k=lq*8+e][col=nt*16+l15] ->
    // LDS(row=lq*8+e, col' = col ^ (8*lq)); 2-way banks (free).
    s16x8 bf0[2], bf1[2], bf2[2];
    #pragma unroll
    for (int nt = 0; nt < 2; ++nt) {
      #pragma unroll
      for (int e = 0; e < 8; ++e) {
        float xv = bA[(lq*8 + e)*32 + ((nt*16 + l15) ^ (lq*8))];
        unsigned short q0, q1, q2; split3(xv, q0, q1, q2);
        bf0[nt][e] = (short)q0; bf1[nt][e] = (short)q1; bf2[nt][e] = (short)q2;
      }
    }
    const bool notlast = (s + 1 < nsteps);
    #pragma unroll
    for (int mt = 0; mt < 8; ++mt) {
      const s16x8 a0 = w0[mt & 3], a1 = w1[mt & 3], a2 = w2[mt & 3];
      if (notlast || mt < 4) {        // prefetch group g+4 into freed slot
        LOADA(mt & 3, s*8 + mt + 4);
      }
      #pragma unroll
      for (int nt = 0; nt < 2; ++nt) {
        f32x4 cc = acc[mt][nt];
        cc = __builtin_amdgcn_mfma_f32_16x16x32_bf16(a0, bf0[nt], cc, 0, 0, 0);
        cc = __builtin_amdgcn_mfma_f32_16x16x32_bf16(a0, bf1[nt], cc, 0, 0, 0);
        cc = __builtin_amdgcn_mfma_f32_16x16x32_bf16(a1, bf0[nt], cc, 0, 0, 0);
        cc = __builtin_amdgcn_mfma_f32_16x16x32_bf16(a0, bf2[nt], cc, 0, 0, 0);
        cc = __builtin_amdgcn_mfma_f32_16x16x32_bf16(a1, bf1[nt], cc, 0, 0, 0);
        cc = __builtin_amdgcn_mfma_f32_16x16x32_bf16(a2, bf0[nt], cc, 0, 0, 0);
        acc[mt][nt] = cc;
      }
    }
    float* t_ = bA; bA = bB; bB = bC; bC = t_;   // rotate B buffers
  }
#undef LOADA
#undef STAGEB
  // epilogue: C/D layout row=(lane>>4)*4+rr, col=lane&15
  float* Pb = part + (size_t)ks*N_BATCH*NH + (size_t)nb*128 + wv*32;
  #pragma unroll
  for (int mt = 0; mt < 8; ++mt)
    #pragma unroll
    for (int nt = 0; nt < 2; ++nt)
      #pragma unroll
      for (int rr = 0; rr < 4; ++rr)
        Pb[(size_t)(mt*16 + lq*4 + rr)*NH + nt*16 + l15] = acc[mt][nt][rr];
}

// ---------------------------------------------------------------------------
// Kernel 4: reduce split-K partials + bias + relu.
// mode 0: emit group-major swizzled bf16 planes (A of next GEMM).
// mode 1: write fp32 rows.
// ---------------------------------------------------------------------------
__global__ __launch_bounds__(256) void reduce_k(
    const float* __restrict__ part, const float* __restrict__ bias,
    unsigned short* __restrict__ AswOut, float* __restrict__ f32out,
    int KS, int mode) {
  const int idx = blockIdx.x*256 + threadIdx.x;     // float4 idx, 131072 total
  float4 s = ((const float4*)part)[idx];
  for (int k2 = 1; k2 < KS; ++k2) {
    float4 p = ((const float4*)part)[(size_t)k2*131072 + idx];
    s.x += p.x; s.y += p.y; s.z += p.z; s.w += p.w;
  }
  float4 bv = ((const float4*)bias)[idx & 1023];
  float v[4];
  v[0] = fmaxf(s.x + bv.x, 0.f); v[1] = fmaxf(s.y + bv.y, 0.f);
  v[2] = fmaxf(s.z + bv.z, 0.f); v[3] = fmaxf(s.w + bv.w, 0.f);
  if (mode == 1) {
    float4 o; o.x = v[0]; o.y = v[1]; o.z = v[2]; o.w = v[3];
    ((float4*)f32out)[idx] = o;
  } else {
    int m = idx >> 10, k = (idx & 1023) * 4;
    int S = k >> 5, kg = (k >> 3) & 3, e0 = k & 7;
    size_t base = ((size_t)S*8 + (m >> 4))*1536
                + (size_t)(kg*16 + (m & 15))*8 + e0;
    unsigned short q[3][4];
    #pragma unroll
    for (int e = 0; e < 4; ++e) split3(v[e], q[0][e], q[1][e], q[2][e]);
    #pragma unroll
    for (int p = 0; p < 3; ++p) {
      ushort4 st; st.x=q[p][0]; st.y=q[p][1]; st.z=q[p][2]; st.w=q[p][3];
      *(ushort4*)(AswOut + base + p*512) = st;
    }
  }
}

// ---------------------------------------------------------------------------
// Kernel 5a: transpose Wcls|Wbox into WT[101][4096]
// ---------------------------------------------------------------------------
__global__ __launch_bounds__(256) void head_transpose(
    const float* __restrict__ Wcls, const float* __restrict__ Wbox,
    float* __restrict__ WT) {
  const int c = blockIdx.x;
  const float* src; int stride;
  if (c < NCLS) { src = Wcls + c; stride = NCLS; }
  else          { src = Wbox + (c - NCLS); stride = NBOX; }
  for (int k = threadIdx.x; k < NH; k += 256)
    WT[(size_t)c*NH + k] = src[(size_t)k*stride];
}

// ---------------------------------------------------------------------------
// Kernel 5b: one wave per (n, col): float4 dot over K=4096 + shuffle reduce
// ---------------------------------------------------------------------------
__global__ __launch_bounds__(256) void head_dots(
    const float* __restrict__ h2, const float* __restrict__ WT,
    float* __restrict__ hout) {
  const int n = blockIdx.y;
  const int wv = threadIdx.x >> 6, lane = threadIdx.x & 63;
  const int c = blockIdx.x * 4 + wv;
  if (c >= NCLS + NBOX) return;
  const float4* hp = (const float4*)(h2 + (size_t)n*NH);
  const float4* wp = (const float4*)(WT + (size_t)c*NH);
  float s0=0.f, s1=0.f, s2=0.f, s3=0.f;
  #pragma unroll
  for (int it = 0; it < 16; ++it) {
    float4 a = hp[it*64 + lane];
    float4 b = wp[it*64 + lane];
    s0 = fmaf(a.x, b.x, s0); s1 = fmaf(a.y, b.y, s1);
    s2 = fmaf(a.z, b.z, s2); s3 = fmaf(a.w, b.w, s3);
  }
  float v = (s0 + s1) + (s2 + s3);
  #pragma unroll
  for (int m = 32; m >= 1; m >>= 1) v += __shfl_xor(v, m, 64);
  if (lane == 0) hout[n*128 + c] = v;
}

// ---------------------------------------------------------------------------
// Kernel 5c: softmax(21) + bbox(80) from stored dots.
// ---------------------------------------------------------------------------
__global__ __launch_bounds__(128) void head_final(
    const float* __restrict__ hout, const int* __restrict__ rp,
    float* __restrict__ out) {
  const int n = blockIdx.x, tid = threadIdx.x;
  __shared__ float logits[NCLS];
  __shared__ float red[2];
  if (tid < NCLS) logits[tid] = hout[n*128 + tid];
  __syncthreads();
  if (tid == 0) {
    float m = logits[0];
    for (int i = 1; i < NCLS; ++i) m = fmaxf(m, logits[i]);
    float s = 0.f;
    for (int i = 0; i < NCLS; ++i) s += expf(logits[i] - m);
    red[0] = m; red[1] = s;
  }
  __syncthreads();
  if (tid < NCLS) {
    out[(size_t)n*NCLS + tid] = expf(logits[tid] - red[0]) / red[1];
  } else if (tid < NCLS + NBOX) {
    const int j = tid - NCLS;
    const float t  = hout[n*128 + tid];
    const float rf = (float)rp[n*4+0];
    const float cf = (float)rp[n*4+1];
    const float wf = (float)rp[n*4+2];
    const float hf = (float)rp[n*4+3];
    float p;
    switch (j & 3) {
      case 0:  p = ceilf (__fmul_rn(__fadd_rn(__fmul_rn(wf, t), rf), 16.f)) - 1.f; break;
      case 1:  p = ceilf (__fmul_rn(__fadd_rn(__fmul_rn(hf, t), cf), 16.f)) - 1.f; break;
      case 2:  p = floorf(__fmul_rn(__fmul_rn(wf, expf(t)), 16.f)) + 1.f; break;
      default: p = floorf(__fmul_rn(__fmul_rn(hf, expf(t)), 16.f)) + 1.f; break;
    }
    out[(size_t)N_BATCH*NCLS + (size_t)n*NBOX + j] = p;
  }
}

// ---------------------------------------------------------------------------
extern "C" void kernel_launch(void* const* d_in, const int* in_sizes, int n_in,
                              void* d_out, int out_size, void* d_ws, size_t ws_size,
                              hipStream_t stream) {
  const float* x    = (const float*)d_in[0];
  const int*   rp   = (const int*)  d_in[1];
  const float* W1   = (const float*)d_in[2];
  const float* b1   = (const float*)d_in[3];
  const float* W2   = (const float*)d_in[4];
  const float* b2   = (const float*)d_in[5];
  const float* Wcls = (const float*)d_in[6];
  const float* Wbox = (const float*)d_in[7];
  float* out = (float*)d_out;

  // ws: flat | Asw1 | Asw2 | h2f | WT | hout | part  (~71 MB; ws ≈ 1.6 GB)
  char* wp = (char*)d_ws;
  float* flat = (float*)wp;           wp += (size_t)N_BATCH*K1*4;
  unsigned short* Asw1 = (unsigned short*)wp; wp += (size_t)STEPS1*24576;
  unsigned short* Asw2 = (unsigned short*)wp; wp += (size_t)STEPS2*24576;
  float* h2f = (float*)wp;            wp += (size_t)N_BATCH*NH*4;
  float* WT  = (float*)wp;            wp += (size_t)(NCLS+NBOX)*NH*4;
  float* hout = (float*)wp;           wp += (size_t)N_BATCH*128*4;
  float* part = (float*)wp;
  const size_t fixed = (size_t)(wp - (char*)d_ws);
  const size_t slab = (size_t)N_BATCH*NH*4;       // 2 MB per partial
  int KS1 = 16, KS2 = 16;                          // grids 512 = 2 blocks/CU
  if (fixed + 16*slab > ws_size) { KS1 = 8; KS2 = 8; }

  pool_kernel<<<dim3(64, 128), 256, 0, stream>>>(x, rp, flat);
  convert_kernel<<<dim3(STEPS1), 256, 0, stream>>>(flat, Asw1, K1);
  head_transpose<<<dim3(NCLS + NBOX), 256, 0, stream>>>(Wcls, Wbox, WT);

  gemm_v6<<<dim3(32, KS1), 256, 0, stream>>>(Asw1, W1, part, STEPS1/KS1);
  reduce_k<<<dim3(512), 256, 0, stream>>>(part, b1, Asw2, nullptr, KS1, 0);

  gemm_v6<<<dim3(32, KS2), 256, 0, stream>>>(Asw2, W2, part, STEPS2/KS2);
  reduce_k<<<dim3(512), 256, 0, stream>>>(part, b2, nullptr, h2f, KS2, 1);

  head_dots<<<dim3(26, 128), 256, 0, stream>>>(h2f, WT, hout);
  head_final<<<dim3(128), 128, 0, stream>>>(hout, rp, out);
}

// Round 10
// 299.269 us; speedup vs baseline: 1.2889x; 1.0448x over previous
//
#include <hip/hip_runtime.h>
#include <hip/hip_bf16.h>
#include <math.h>

#define N_BATCH 128
#define C_CH    512
#define HF      38
#define WF      38
#define K1      25088   // 512*49
#define NH      4096
#define NCLS    21
#define NBOX    80
#define STEPS1  784     // K1/32
#define STEPS2  128     // NH/32

typedef __attribute__((ext_vector_type(8))) short s16x8;
typedef __attribute__((ext_vector_type(4))) float f32x4;

// fp32 -> 3x bf16 split (RNE): x ~= b0+b1+b2, residual ~ |x|*2^-25
__device__ __forceinline__ unsigned short bf_rne(float x) {
  unsigned u = __float_as_uint(x);
  return (unsigned short)((u + 0x7FFFu + ((u >> 16) & 1u)) >> 16);
}
__device__ __forceinline__ float bf2f(unsigned short b) {
  return __uint_as_float(((unsigned)b) << 16);
}
__device__ __forceinline__ void split3(float x, unsigned short& q0,
                                       unsigned short& q1, unsigned short& q2) {
  q0 = bf_rne(x); float r1 = x - bf2f(q0);
  q1 = bf_rne(r1); float r2 = r1 - bf2f(q1);
  q2 = bf_rne(r2);
}

__device__ __forceinline__ void gload16(const void* g, void* l) {
  __builtin_amdgcn_global_load_lds(
      (const __attribute__((address_space(1))) unsigned int*)g,
      (__attribute__((address_space(3))) unsigned int*)l, 16, 0, 0);
}

// ---------------------------------------------------------------------------
// Kernel 1: ROI crop + adaptive 7x7 maxpool -> 3 bf16 planes directly, in
// GROUP-MAJOR fragment order: group g = S*8 + mt; short addr =
// g*1536 + plane*512 + (kg*16 + mlo)*8 + e, with m=n, k=(cb*8+ch)*49+ij,
// S=k>>5, kg=(k>>3)&3, e=k&7. (flat intermediate + convert kernel deleted)
// ---------------------------------------------------------------------------
__global__ __launch_bounds__(256) void pool_kernel(
    const float* __restrict__ x, const int* __restrict__ rp,
    unsigned short* __restrict__ Asw) {
  const int n = blockIdx.y, cb = blockIdx.x, tid = threadIdx.x;
  const int r = rp[n*4+0], c = rp[n*4+1], w = rp[n*4+2], h = rp[n*4+3];
  __shared__ float tile[8][24][25];
  const int ch = tid >> 5, l32 = tid & 31;
  const float* xc = x + (((size_t)(n*C_CH + cb*8 + ch))*HF + c)*WF + r;
  for (int y = 0; y < h; ++y)
    for (int xx = l32; xx < w; xx += 32)
      tile[ch][y][xx] = xc[y*WF + xx];
  __syncthreads();
  const int mt = n >> 4, mlo = n & 15;
  for (int o = tid; o < 8*49; o += 256) {
    int ch2 = o / 49, ij = o - ch2*49, i = ij / 7, j = ij - i*7;
    int rs = (i*h)/7, re = ((i+1)*h + 6)/7;
    int cs = (j*w)/7, ce = ((j+1)*w + 6)/7;
    float m = -INFINITY;
    for (int y = rs; y < re; ++y)
      for (int xx = cs; xx < ce; ++xx)
        m = fmaxf(m, tile[ch2][y][xx]);
    int k = (cb*8 + ch2)*49 + ij;
    int S = k >> 5, kg = (k >> 3) & 3, e = k & 7;
    size_t base = ((size_t)S*8 + mt)*1536 + (size_t)(kg*16 + mlo)*8 + e;
    unsigned short q0, q1, q2; split3(m, q0, q1, q2);
    Asw[base] = q0; Asw[base + 512] = q1; Asw[base + 1024] = q2;
  }
}

// ---------------------------------------------------------------------------
// Kernel 2: barrier-free split-K MFMA GEMM, 2x2 wave decomposition.
// BM=128, BN=128, BK=32, 4 waves: wave (wr=wv>>1, wc=wv&1) owns
// rows [wr*64, wr*64+64) (4 mt) x cols [wc*64, wc*64+64) (4 nt).
// A: per-wave 4-slot register window over its 4 mt-groups, prefetch one
//    full step ahead (group-major layout; halved per-wave traffic vs v6).
// B: wave-private double-buffered 8KB LDS slice (64 cols), duplicated
//    between the wr-pair (2nd read = L2 hit; keeps kernel barrier-free),
//    pre-swizzled source cols so fragment reads are 2-way banked (free).
// Sync: counted s_waitcnt vmcnt(20) steady / vmcnt(12) last. No barriers.
// ---------------------------------------------------------------------------
__global__ __launch_bounds__(256, 2) void gemm_v7(
    const unsigned short* __restrict__ Asw, const float* __restrict__ B,
    float* __restrict__ part, const int nsteps) {
  __shared__ float Bsm[4][2][32][64];   // [wave][dbuf][k][col'] = 64 KB
  const int tid = threadIdx.x, lane = tid & 63, wv = tid >> 6;
  const int wr = wv >> 1, wc = wv & 1;
  const int nb = blockIdx.x, ks = blockIdx.y;
  const int l15 = lane & 15, lq = lane >> 4;
  const unsigned short* Ag = Asw + (size_t)ks*nsteps*12288 + lane*8;
  const int srow4 = lane >> 4, scol16 = lane & 15;   // staging lane map
  const float* Bg = B + ((size_t)ks*nsteps*32 + srow4)*NH
                  + (size_t)nb*128 + wc*64;

  f32x4 acc[4][4];
  #pragma unroll
  for (int i = 0; i < 4; ++i)
    #pragma unroll
    for (int j = 0; j < 4; ++j) acc[i][j] = (f32x4){0.f, 0.f, 0.f, 0.f};

  s16x8 w0[4], w1[4], w2[4];            // 4-slot A window (this wave's 4 mt)
#define LOADA(slot, g) do { \
    const unsigned short* ap_ = Ag + (size_t)(g)*1536; \
    w0[slot] = *(const s16x8*)ap_; \
    w1[slot] = *(const s16x8*)(ap_ + 512); \
    w2[slot] = *(const s16x8*)(ap_ + 1024); } while (0)

  float* ldsb = &Bsm[wv][0][0][0];      // this wave's 2 buffers (8KB each)
#define STAGEB(s, buf) do { \
    float* dst_ = ldsb + (buf)*2048; \
    _Pragma("unroll") \
    for (int i_ = 0; i_ < 8; ++i_) \
      gload16(Bg + ((size_t)(s)*32 + i_*4)*NH \
                 + ((scol16*4) ^ (8*((i_ >> 1) & 3))), dst_ + i_*256); \
    } while (0)

  STAGEB(0, 0);
  LOADA(0, wr*4 + 0); LOADA(1, wr*4 + 1);
  LOADA(2, wr*4 + 2); LOADA(3, wr*4 + 3);

  for (int s = 0; s < nsteps; ++s) {
    if (s + 1 < nsteps) {
      STAGEB(s + 1, (s + 1) & 1);
      asm volatile("s_waitcnt vmcnt(20)" ::: "memory");  // B(s) landed
    } else {
      asm volatile("s_waitcnt vmcnt(12)" ::: "memory");
    }
    // B fragments: lane needs B[k=lq*8+e][col=nt*16+l15] at LDS
    // (row, col ^ (8*lq)); 2-way banks (free).
    const float* bb = ldsb + (s & 1)*2048;
    s16x8 bf0[4], bf1[4], bf2[4];
    #pragma unroll
    for (int nt = 0; nt < 4; ++nt) {
      #pragma unroll
      for (int e = 0; e < 8; ++e) {
        float xv = bb[(lq*8 + e)*64 + ((nt*16 + l15) ^ (lq*8))];
        unsigned short q0, q1, q2; split3(xv, q0, q1, q2);
        bf0[nt][e] = (short)q0; bf1[nt][e] = (short)q1; bf2[nt][e] = (short)q2;
      }
    }
    #pragma unroll
    for (int ml = 0; ml < 4; ++ml) {
      const s16x8 a0 = w0[ml], a1 = w1[ml], a2 = w2[ml];
      LOADA(ml, (s + 1)*8 + wr*4 + ml);   // next step (overrun stays in ws)
      #pragma unroll
      for (int nt = 0; nt < 4; ++nt) {
        f32x4 cc = acc[ml][nt];
        cc = __builtin_amdgcn_mfma_f32_16x16x32_bf16(a0, bf0[nt], cc, 0, 0, 0);
        cc = __builtin_amdgcn_mfma_f32_16x16x32_bf16(a0, bf1[nt], cc, 0, 0, 0);
        cc = __builtin_amdgcn_mfma_f32_16x16x32_bf16(a1, bf0[nt], cc, 0, 0, 0);
        cc = __builtin_amdgcn_mfma_f32_16x16x32_bf16(a0, bf2[nt], cc, 0, 0, 0);
        cc = __builtin_amdgcn_mfma_f32_16x16x32_bf16(a1, bf1[nt], cc, 0, 0, 0);
        cc = __builtin_amdgcn_mfma_f32_16x16x32_bf16(a2, bf0[nt], cc, 0, 0, 0);
        acc[ml][nt] = cc;
      }
    }
  }
#undef LOADA
#undef STAGEB
  // epilogue: C/D layout row=(lane>>4)*4+rr, col=lane&15
  float* Pb = part + (size_t)ks*N_BATCH*NH + (size_t)nb*128 + wc*64;
  #pragma unroll
  for (int ml = 0; ml < 4; ++ml)
    #pragma unroll
    for (int nt = 0; nt < 4; ++nt)
      #pragma unroll
      for (int rr = 0; rr < 4; ++rr)
        Pb[(size_t)((wr*4 + ml)*16 + lq*4 + rr)*NH + nt*16 + l15]
            = acc[ml][nt][rr];
}

// ---------------------------------------------------------------------------
// Kernel 3: reduce split-K partials + bias + relu.
// mode 0: emit group-major swizzled bf16 planes (A of next GEMM).
// mode 1: write fp32 rows.
// ---------------------------------------------------------------------------
__global__ __launch_bounds__(256) void reduce_k(
    const float* __restrict__ part, const float* __restrict__ bias,
    unsigned short* __restrict__ AswOut, float* __restrict__ f32out,
    int KS, int mode) {
  const int idx = blockIdx.x*256 + threadIdx.x;     // float4 idx, 131072 total
  float4 s = ((const float4*)part)[idx];
  for (int k2 = 1; k2 < KS; ++k2) {
    float4 p = ((const float4*)part)[(size_t)k2*131072 + idx];
    s.x += p.x; s.y += p.y; s.z += p.z; s.w += p.w;
  }
  float4 bv = ((const float4*)bias)[idx & 1023];
  float v[4];
  v[0] = fmaxf(s.x + bv.x, 0.f); v[1] = fmaxf(s.y + bv.y, 0.f);
  v[2] = fmaxf(s.z + bv.z, 0.f); v[3] = fmaxf(s.w + bv.w, 0.f);
  if (mode == 1) {
    float4 o; o.x = v[0]; o.y = v[1]; o.z = v[2]; o.w = v[3];
    ((float4*)f32out)[idx] = o;
  } else {
    int m = idx >> 10, k = (idx & 1023) * 4;
    int S = k >> 5, kg = (k >> 3) & 3, e0 = k & 7;
    size_t base = ((size_t)S*8 + (m >> 4))*1536
                + (size_t)(kg*16 + (m & 15))*8 + e0;
    unsigned short q[3][4];
    #pragma unroll
    for (int e = 0; e < 4; ++e) split3(v[e], q[0][e], q[1][e], q[2][e]);
    #pragma unroll
    for (int p = 0; p < 3; ++p) {
      ushort4 st; st.x=q[p][0]; st.y=q[p][1]; st.z=q[p][2]; st.w=q[p][3];
      *(ushort4*)(AswOut + base + p*512) = st;
    }
  }
}

// ---------------------------------------------------------------------------
// Kernel 4a: transpose Wcls|Wbox into WT[101][4096]
// ---------------------------------------------------------------------------
__global__ __launch_bounds__(256) void head_transpose(
    const float* __restrict__ Wcls, const float* __restrict__ Wbox,
    float* __restrict__ WT) {
  const int c = blockIdx.x;
  const float* src; int stride;
  if (c < NCLS) { src = Wcls + c; stride = NCLS; }
  else          { src = Wbox + (c - NCLS); stride = NBOX; }
  for (int k = threadIdx.x; k < NH; k += 256)
    WT[(size_t)c*NH + k] = src[(size_t)k*stride];
}

// ---------------------------------------------------------------------------
// Kernel 4b: one wave per (n, col): float4 dot over K=4096 + shuffle reduce
// ---------------------------------------------------------------------------
__global__ __launch_bounds__(256) void head_dots(
    const float* __restrict__ h2, const float* __restrict__ WT,
    float* __restrict__ hout) {
  const int n = blockIdx.y;
  const int wv = threadIdx.x >> 6, lane = threadIdx.x & 63;
  const int c = blockIdx.x * 4 + wv;
  if (c >= NCLS + NBOX) return;
  const float4* hp = (const float4*)(h2 + (size_t)n*NH);
  const float4* wp = (const float4*)(WT + (size_t)c*NH);
  float s0=0.f, s1=0.f, s2=0.f, s3=0.f;
  #pragma unroll
  for (int it = 0; it < 16; ++it) {
    float4 a = hp[it*64 + lane];
    float4 b = wp[it*64 + lane];
    s0 = fmaf(a.x, b.x, s0); s1 = fmaf(a.y, b.y, s1);
    s2 = fmaf(a.z, b.z, s2); s3 = fmaf(a.w, b.w, s3);
  }
  float v = (s0 + s1) + (s2 + s3);
  #pragma unroll
  for (int m = 32; m >= 1; m >>= 1) v += __shfl_xor(v, m, 64);
  if (lane == 0) hout[n*128 + c] = v;
}

// ---------------------------------------------------------------------------
// Kernel 4c: softmax(21) + bbox(80) from stored dots.
// ---------------------------------------------------------------------------
__global__ __launch_bounds__(128) void head_final(
    const float* __restrict__ hout, const int* __restrict__ rp,
    float* __restrict__ out) {
  const int n = blockIdx.x, tid = threadIdx.x;
  __shared__ float logits[NCLS];
  __shared__ float red[2];
  if (tid < NCLS) logits[tid] = hout[n*128 + tid];
  __syncthreads();
  if (tid == 0) {
    float m = logits[0];
    for (int i = 1; i < NCLS; ++i) m = fmaxf(m, logits[i]);
    float s = 0.f;
    for (int i = 0; i < NCLS; ++i) s += expf(logits[i] - m);
    red[0] = m; red[1] = s;
  }
  __syncthreads();
  if (tid < NCLS) {
    out[(size_t)n*NCLS + tid] = expf(logits[tid] - red[0]) / red[1];
  } else if (tid < NCLS + NBOX) {
    const int j = tid - NCLS;
    const float t  = hout[n*128 + tid];
    const float rf = (float)rp[n*4+0];
    const float cf = (float)rp[n*4+1];
    const float wf = (float)rp[n*4+2];
    const float hf = (float)rp[n*4+3];
    float p;
    switch (j & 3) {
      case 0:  p = ceilf (__fmul_rn(__fadd_rn(__fmul_rn(wf, t), rf), 16.f)) - 1.f; break;
      case 1:  p = ceilf (__fmul_rn(__fadd_rn(__fmul_rn(hf, t), cf), 16.f)) - 1.f; break;
      case 2:  p = floorf(__fmul_rn(__fmul_rn(wf, expf(t)), 16.f)) + 1.f; break;
      default: p = floorf(__fmul_rn(__fmul_rn(hf, expf(t)), 16.f)) + 1.f; break;
    }
    out[(size_t)N_BATCH*NCLS + (size_t)n*NBOX + j] = p;
  }
}

// ---------------------------------------------------------------------------
extern "C" void kernel_launch(void* const* d_in, const int* in_sizes, int n_in,
                              void* d_out, int out_size, void* d_ws, size_t ws_size,
                              hipStream_t stream) {
  const float* x    = (const float*)d_in[0];
  const int*   rp   = (const int*)  d_in[1];
  const float* W1   = (const float*)d_in[2];
  const float* b1   = (const float*)d_in[3];
  const float* W2   = (const float*)d_in[4];
  const float* b2   = (const float*)d_in[5];
  const float* Wcls = (const float*)d_in[6];
  const float* Wbox = (const float*)d_in[7];
  float* out = (float*)d_out;

  // ws: Asw1 | Asw2 | h2f | WT | hout | part  (~60 MB; ws ≈ 1.6 GB)
  char* wp = (char*)d_ws;
  unsigned short* Asw1 = (unsigned short*)wp; wp += (size_t)STEPS1*24576;
  unsigned short* Asw2 = (unsigned short*)wp; wp += (size_t)STEPS2*24576;
  float* h2f = (float*)wp;            wp += (size_t)N_BATCH*NH*4;
  float* WT  = (float*)wp;            wp += (size_t)(NCLS+NBOX)*NH*4;
  float* hout = (float*)wp;           wp += (size_t)N_BATCH*128*4;
  float* part = (float*)wp;
  const size_t fixed = (size_t)(wp - (char*)d_ws);
  const size_t slab = (size_t)N_BATCH*NH*4;       // 2 MB per partial
  int KS1 = 16, KS2 = 16;                          // grids 512 = 2 blocks/CU
  if (fixed + 16*slab > ws_size) { KS1 = 8; KS2 = 8; }

  pool_kernel<<<dim3(64, 128), 256, 0, stream>>>(x, rp, Asw1);
  head_transpose<<<dim3(NCLS + NBOX), 256, 0, stream>>>(Wcls, Wbox, WT);

  gemm_v7<<<dim3(32, KS1), 256, 0, stream>>>(Asw1, W1, part, STEPS1/KS1);
  reduce_k<<<dim3(512), 256, 0, stream>>>(part, b1, Asw2, nullptr, KS1, 0);

  gemm_v7<<<dim3(32, KS2), 256, 0, stream>>>(Asw2, W2, part, STEPS2/KS2);
  reduce_k<<<dim3(512), 256, 0, stream>>>(part, b2, nullptr, h2f, KS2, 1);

  head_dots<<<dim3(26, 128), 256, 0, stream>>>(h2f, WT, hout);
  head_final<<<dim3(128), 128, 0, stream>>>(hout, rp, out);
}